// Round 8
// baseline (2545.606 us; speedup 1.0000x reference)
//
#include <hip/hip_runtime.h>
#include <math.h>

// ClusterNet round-8 (= round-6 design, second resubmit; GPU acquisition
// timed out twice before the kernel ever ran).
//  A-partial: wave-per-quarter (wv=d-quarter, lane=row) -> mn index is
//    wave-uniform -> s_load (scalar pipe, no LDS). Partials to plds
//    [wv][row][chunk] with rotation swizzle pc(j,ln)=(j+(ln>>1))&3.
//  A-final: (g,q) map sums 4 partials, ss from 8 LDS e-reads + shfl,
//    softmax in 4-lane group, r~ written IN-PLACE to plds[0] (same-slot).
//  Phase B: wave=k-quad, lane=(ph,d4): 32 e b128 + 32 broadcast r b128.
//  LDS exactly 80 KB (2x32KB elds + 16KB plds) -> 2 blocks/CU.

#define N_ROWS 500000
#define D 128
#define K 16
#define TEMP 0.5f
#define EPSV 1e-8f
#define TILE 64
#define BLK 256
#define NITER 11
#define NTILES ((N_ROWS + TILE - 1) / TILE)   // 7813
#define NB 512

typedef const __attribute__((address_space(1))) float4* gas_f4;
typedef __attribute__((address_space(3))) float4* las_f4;

__device__ __forceinline__ void gl_lds16(const float4* g, float4* l) {
    __builtin_amdgcn_global_load_lds((gas_f4)g, (las_f4)l, 16, 0, 0);
}

__global__ void k_init(const float* __restrict__ mu0,
                       float* __restrict__ mn,
                       float* __restrict__ accum) {
    __shared__ float m1[K * D];
    __shared__ float inv[K];
    const int t = threadIdx.x;
    for (int i = t; i < K * D + K; i += 256) accum[i] = 0.0f;
    if (t < K) {
        float ss = 0.0f;
        for (int d = 0; d < D; ++d) { float v = mu0[t * D + d]; ss += v * v; }
        inv[t] = 1.0f / sqrtf(ss);
    }
    __syncthreads();
    for (int i = t; i < K * D; i += 256) m1[i] = mu0[i] * inv[i / D];
    __syncthreads();
    if (t < K) {
        float ss = 0.0f;
        for (int d = 0; d < D; ++d) { float v = m1[t * D + d]; ss += v * v; }
        inv[t] = 1.0f / sqrtf(ss);
    }
    __syncthreads();
    for (int i = t; i < K * D; i += 256) mn[i] = m1[i] * inv[i / D];
}

__global__ __launch_bounds__(BLK) void k_main(const float* __restrict__ e,
                                              const float* __restrict__ mn,
                                              float* __restrict__ accum,
                                              float* __restrict__ r_out,
                                              int write_r) {
    __shared__ float4 elds[2][TILE * 32];   // 2 x 32 KB e tiles (swizzled cols)
    __shared__ float4 plds[4 * TILE * 4];   // 16 KB: [wv][row][chunk(phys)]

    const int t   = threadIdx.x;
    const int wvu = __builtin_amdgcn_readfirstlane(t >> 6);  // wave id, SGPR
    const int ln  = t & 63;       // A-partial row
    const int g   = t >> 2;       // A-final row
    const int q   = t & 3;        // A-final k-quad
    const int ph  = (t >> 5) & 1; // B p-half
    const int d4b = t & 31;       // B float4 column

    const float4* __restrict__ e4  = (const float4*)e;
    const float4* __restrict__ mn4 = (const float4*)mn;

    int tile = blockIdx.x;
    // prologue: issue tile0 prefetch (loop-top vmcnt/barrier covers the wait)
    #pragma unroll
    for (int i = 0; i < 8; ++i) {
        const int sigma = wvu * 512 + i * 64 + ln;
        const int sg = sigma >> 5, s = sigma & 31;
        int row = tile * TILE + sg; if (row > N_ROWS - 1) row = N_ROWS - 1;
        gl_lds16(e4 + row * 32 + (s ^ (sg & 31)), &elds[0][wvu * 512 + i * 64]);
    }

    float acc[4][4];
    #pragma unroll
    for (int a = 0; a < 4; ++a)
        #pragma unroll
        for (int b = 0; b < 4; ++b) acc[a][b] = 0.0f;
    float crq[4] = {0.f, 0.f, 0.f, 0.f};

    int buf = 0;
    for (; tile < NTILES; tile += NB, buf ^= 1) {
        const int base = tile * TILE;
        const int nt = tile + NB;
        if (nt < NTILES) {                   // async prefetch next tile
            #pragma unroll
            for (int i = 0; i < 8; ++i) {
                const int sigma = wvu * 512 + i * 64 + ln;
                const int sg = sigma >> 5, s = sigma & 31;
                int row = nt * TILE + sg; if (row > N_ROWS - 1) row = N_ROWS - 1;
                gl_lds16(e4 + row * 32 + (s ^ (sg & 31)), &elds[buf ^ 1][wvu * 512 + i * 64]);
            }
            asm volatile("s_waitcnt vmcnt(8)" ::: "memory");   // cur tile landed
        } else {
            asm volatile("s_waitcnt vmcnt(0)" ::: "memory");
        }
        __builtin_amdgcn_sched_barrier(0);
        __builtin_amdgcn_s_barrier();        // cur elds ready
        __builtin_amdgcn_sched_barrier(0);

        const float4* __restrict__ eb = (const float4*)elds[buf];

        // ---- A-partial: wave wvu covers chunks c*4+wvu of row ln ----
        float dp[K];
        #pragma unroll
        for (int k = 0; k < K; ++k) dp[k] = 0.0f;
        #pragma unroll
        for (int c = 0; c < 8; ++c) {
            const float4 ev = eb[(ln << 5) + (((c << 2) + wvu) ^ (ln & 31))];
            #pragma unroll
            for (int k = 0; k < K; ++k) {
                const float4 m = mn4[k * 32 + (c << 2) + wvu];  // wave-uniform -> s_load
                dp[k] += ev.x * m.x + ev.y * m.y + ev.z * m.z + ev.w * m.w;
            }
        }
        #pragma unroll
        for (int j = 0; j < 4; ++j) {
            float4 v;
            v.x = dp[j * 4 + 0]; v.y = dp[j * 4 + 1];
            v.z = dp[j * 4 + 2]; v.w = dp[j * 4 + 3];
            plds[wvu * 256 + ln * 4 + ((j + (ln >> 1)) & 3)] = v;
        }
        asm volatile("s_waitcnt lgkmcnt(0)" ::: "memory");
        __builtin_amdgcn_sched_barrier(0);
        __builtin_amdgcn_s_barrier();        // plds partials ready
        __builtin_amdgcn_sched_barrier(0);

        // ---- A-final: thread (g,q) owns ks q*4..q*4+3 of row g ----
        const int row = base + g;
        const bool valid = row < N_ROWS;
        float4 dsum = {0.f, 0.f, 0.f, 0.f};
        #pragma unroll
        for (int w2 = 0; w2 < 4; ++w2) {
            const float4 v = plds[w2 * 256 + g * 4 + ((q + (g >> 1)) & 3)];
            dsum.x += v.x; dsum.y += v.y; dsum.z += v.z; dsum.w += v.w;
        }
        float ssp = 0.0f;
        #pragma unroll
        for (int c = 0; c < 8; ++c) {
            const float4 evv = eb[(g << 5) + (((q << 3) + c) ^ (g & 31))];
            ssp += evv.x * evv.x + evv.y * evv.y + evv.z * evv.z + evv.w * evv.w;
        }
        ssp += __shfl_xor(ssp, 1);
        ssp += __shfl_xor(ssp, 2);
        const float nrm  = sqrtf(ssp);
        const float binv = 1.0f / nrm;
        const float ainv = 1.0f / (nrm + EPSV);

        float d0 = -TEMP * binv * dsum.x;
        float d1 = -TEMP * binv * dsum.y;
        float d2 = -TEMP * binv * dsum.z;
        float d3 = -TEMP * binv * dsum.w;
        float mx = fmaxf(fmaxf(d0, d1), fmaxf(d2, d3));
        mx = fmaxf(mx, __shfl_xor(mx, 1));
        mx = fmaxf(mx, __shfl_xor(mx, 2));
        float e0 = __expf(d0 - mx), e1 = __expf(d1 - mx);
        float e2 = __expf(d2 - mx), e3 = __expf(d3 - mx);
        float sm = e0 + e1 + e2 + e3;
        sm += __shfl_xor(sm, 1);
        sm += __shfl_xor(sm, 2);
        const float isum = 1.0f / sm;
        const float r0 = valid ? e0 * isum : 0.0f;
        const float r1 = valid ? e1 * isum : 0.0f;
        const float r2 = valid ? e2 * isum : 0.0f;
        const float r3 = valid ? e3 * isum : 0.0f;
        crq[0] += r0; crq[1] += r1; crq[2] += r2; crq[3] += r3;

        float4 rt;                            // r~ = r * ainv
        rt.x = r0 * ainv; rt.y = r1 * ainv; rt.z = r2 * ainv; rt.w = r3 * ainv;
        plds[g * 4 + ((q + (g >> 1)) & 3)] = rt;   // in-place, same-slot-only

        if (write_r && valid) {
            float4 rv; rv.x = r0; rv.y = r1; rv.z = r2; rv.w = r3;
            ((float4*)(r_out + row * K))[q] = rv;
        }
        asm volatile("s_waitcnt lgkmcnt(0)" ::: "memory");
        __builtin_amdgcn_sched_barrier(0);
        __builtin_amdgcn_s_barrier();        // r~ ready
        __builtin_amdgcn_sched_barrier(0);

        // ---- Phase B: wave=k-quad wvu, lane=(ph,d4b); 32 p's each ----
        #pragma unroll 8
        for (int i = 0; i < 32; ++i) {
            const int p = ph * 32 + i;
            const float4 ev = eb[(p << 5) + (d4b ^ i)];
            const float4 rr = plds[p * 4 + ((wvu + (p >> 1)) & 3)];  // broadcast
            acc[0][0] += rr.x * ev.x; acc[0][1] += rr.x * ev.y;
            acc[0][2] += rr.x * ev.z; acc[0][3] += rr.x * ev.w;
            acc[1][0] += rr.y * ev.x; acc[1][1] += rr.y * ev.y;
            acc[1][2] += rr.y * ev.z; acc[1][3] += rr.y * ev.w;
            acc[2][0] += rr.z * ev.x; acc[2][1] += rr.z * ev.y;
            acc[2][2] += rr.z * ev.z; acc[2][3] += rr.z * ev.w;
            acc[3][0] += rr.w * ev.x; acc[3][1] += rr.w * ev.y;
            acc[3][2] += rr.w * ev.z; acc[3][3] += rr.w * ev.w;
        }
        __builtin_amdgcn_sched_barrier(0);
        __builtin_amdgcn_s_barrier();        // elds/plds consumption done
        __builtin_amdgcn_sched_barrier(0);
    }

    // ---- merge cluster_mean: (wvu,ph,d4b) -> ks wvu*4.., d d4b*4.. ----
    #pragma unroll
    for (int kk = 0; kk < 4; ++kk)
        #pragma unroll
        for (int j = 0; j < 4; ++j)
            atomicAdd(&accum[(wvu * 4 + kk) * D + d4b * 4 + j], acc[kk][j]);

    // ---- block-reduce cluster_r (crq on (g,q) map), then 16 atomics ----
    __syncthreads();
    float* fld = (float*)plds;
    fld[t * 4 + 0] = crq[0]; fld[t * 4 + 1] = crq[1];
    fld[t * 4 + 2] = crq[2]; fld[t * 4 + 3] = crq[3];
    __syncthreads();
    if (t < K) {
        const int qq = t >> 2, jj = t & 3;
        float s = 0.0f;
        #pragma unroll 4
        for (int i = 0; i < 64; ++i) s += fld[(i * 4 + qq) * 4 + jj];
        atomicAdd(&accum[K * D + t], s);
    }
}

__global__ void k_update(float* __restrict__ accum,
                         float* __restrict__ mn,
                         float* __restrict__ mu_out,
                         int last) {
    __shared__ float mu[K * D];
    __shared__ float inv[K];
    const int t = threadIdx.x;
    for (int i = t; i < K * D; i += 256)
        mu[i] = accum[i] / accum[K * D + i / D];
    __syncthreads();
    if (last) {
        for (int i = t; i < K * D; i += 256) mu_out[i] = mu[i];
    } else {
        if (t < K) {
            float ssq = 0.0f;
            for (int d = 0; d < D; ++d) { float v = mu[t * D + d]; ssq += v * v; }
            inv[t] = 1.0f / sqrtf(ssq);
        }
        __syncthreads();
        for (int i = t; i < K * D; i += 256) mu[i] *= inv[i / D];
        __syncthreads();
        if (t < K) {
            float ssq = 0.0f;
            for (int d = 0; d < D; ++d) { float v = mu[t * D + d]; ssq += v * v; }
            inv[t] = 1.0f / sqrtf(ssq);
        }
        __syncthreads();
        for (int i = t; i < K * D; i += 256) mn[i] = mu[i] * inv[i / D];
    }
    __syncthreads();
    for (int i = t; i < K * D + K; i += 256) accum[i] = 0.0f;
}

extern "C" void kernel_launch(void* const* d_in, const int* in_sizes, int n_in,
                              void* d_out, int out_size, void* d_ws, size_t ws_size,
                              hipStream_t stream) {
    const float* e   = (const float*)d_in[0];   // [N, D] f32
    const float* mu0 = (const float*)d_in[1];   // [K, D] f32
    float* out = (float*)d_out;                 // mu [K*D] then r [N*K]
    float* ws  = (float*)d_ws;

    float* mn    = ws;            // [K*D]
    float* accum = ws + K * D;    // [K*D + K]
    float* r_out = out + K * D;

    hipLaunchKernelGGL(k_init, dim3(1), dim3(256), 0, stream, mu0, mn, accum);
    for (int it = 0; it < NITER; ++it) {
        const int last = (it == NITER - 1) ? 1 : 0;
        hipLaunchKernelGGL(k_main, dim3(NB), dim3(BLK), 0, stream,
                           e, mn, accum, r_out, last);
        hipLaunchKernelGGL(k_update, dim3(1), dim3(256), 0, stream,
                           accum, mn, out, last);
    }
}